// Round 1
// baseline (2397.526 us; speedup 1.0000x reference)
//
#include <hip/hip_runtime.h>

// Problem constants (fixed by the reference)
constexpr int Mdim = 32;      // b*c
constexpr int Kdim = 16384;   // rows*cols
constexpr int Ndim = 16384;   // h*w

// Tiling
constexpr int KC   = 256;            // k-chunk per block
constexpr int TPB  = 256;            // threads per block
constexpr int NPT  = 4;              // columns per thread (float4)
constexpr int NT   = TPB * NPT;      // 1024 columns per block
constexpr int NTILES = Ndim / NT;    // 16
constexpr int KTILES = Kdim / KC;    // 64

__device__ __forceinline__ void fma4(float4& a, float s, const float4& v) {
    a.x = fmaf(s, v.x, a.x);
    a.y = fmaf(s, v.y, a.y);
    a.z = fmaf(s, v.z, a.z);
    a.w = fmaf(s, v.w, a.w);
}

__global__ __launch_bounds__(TPB, 3)
void ht_gemm(const float* __restrict__ image,   // (32, 16384) row-major
             const float* __restrict__ vote,    // (16384, 16384) row-major
             float* __restrict__ out)           // (32, 16384), pre-zeroed
{
    __shared__ float xs[KC * Mdim];   // xs[kk*32 + m] = relu(image[m][k0+kk]) / 128

    const int tid    = threadIdx.x;
    const int ntile  = blockIdx.x % NTILES;
    const int kchunk = blockIdx.x / NTILES;
    const int k0     = kchunk * KC;
    const int n0     = ntile * NT + tid * NPT;

    constexpr float scale = 1.0f / 128.0f;  // power of two: exact fold

    // Stage x chunk (transposed, relu'd, pre-scaled) into LDS.
    // Consecutive lanes -> consecutive LDS addresses (conflict-free writes);
    // global reads are line-reused via L1 across the idx loop.
    for (int idx = tid; idx < KC * Mdim; idx += TPB) {
        const int kk = idx >> 5;    // idx / 32
        const int m  = idx & 31;
        const float v = image[(size_t)m * Kdim + (k0 + kk)];
        xs[idx] = fmaxf(v, 0.0f) * scale;
    }
    __syncthreads();

    float4 acc[Mdim];
    #pragma unroll
    for (int m = 0; m < Mdim; ++m) acc[m] = make_float4(0.f, 0.f, 0.f, 0.f);

    const float* vptr = vote + (size_t)k0 * Ndim + n0;

    #pragma unroll 2
    for (int kk = 0; kk < KC; ++kk) {
        const float4 v = *reinterpret_cast<const float4*>(vptr);
        vptr += Ndim;
        const float4* x4 = reinterpret_cast<const float4*>(&xs[kk * Mdim]);
        #pragma unroll
        for (int g = 0; g < 8; ++g) {
            const float4 xv = x4[g];       // ds_read_b128, wave-uniform broadcast
            const int mb = g * 4;
            fma4(acc[mb + 0], xv.x, v);
            fma4(acc[mb + 1], xv.y, v);
            fma4(acc[mb + 2], xv.z, v);
            fma4(acc[mb + 3], xv.w, v);
        }
    }

    // Combine k-chunk partials with native fp32 atomics (output is 2 MB ->
    // stays cache-resident; ~64 adds per cell total, low contention).
    #pragma unroll
    for (int m = 0; m < Mdim; ++m) {
        float* o = out + (size_t)m * Ndim + n0;
        unsafeAtomicAdd(o + 0, acc[m].x);
        unsafeAtomicAdd(o + 1, acc[m].y);
        unsafeAtomicAdd(o + 2, acc[m].z);
        unsafeAtomicAdd(o + 3, acc[m].w);
    }
}

extern "C" void kernel_launch(void* const* d_in, const int* in_sizes, int n_in,
                              void* d_out, int out_size, void* d_ws, size_t ws_size,
                              hipStream_t stream) {
    const float* image = (const float*)d_in[0];   // (2,16,128,128) = (32,16384)
    const float* vote  = (const float*)d_in[1];   // (128,128,128,128) = (16384,16384)
    float* out = (float*)d_out;                   // (2,16,128,128) = (32,16384)

    // d_out is poisoned before every launch; atomics need zeroed output.
    (void)hipMemsetAsync(out, 0, (size_t)out_size * sizeof(float), stream);

    dim3 grid(NTILES * KTILES);
    ht_gemm<<<grid, TPB, 0, stream>>>(image, vote, out);
}

// Round 2
// 1423.017 us; speedup vs baseline: 1.6848x; 1.6848x over previous
//
#include <hip/hip_runtime.h>

// Problem constants (fixed by the reference)
constexpr int Mdim = 32;      // b*c
constexpr int Kdim = 16384;   // rows*cols
constexpr int Ndim = 16384;   // h*w

constexpr int TPB  = 256;
constexpr int NPT  = 2;                  // columns per thread (float2)
constexpr int NT   = TPB * NPT;          // 512 columns per block
constexpr int NTILES = Ndim / NT;        // 32
constexpr int U    = 8;                  // V prefetch depth (outstanding loads/thread)

// ---------------------------------------------------------------------------
// Phase 0: xT[k][m] = relu(image[m][k]) / 128   (2 MB, built once per launch)
// ---------------------------------------------------------------------------
__global__ __launch_bounds__(TPB)
void build_xt(const float* __restrict__ image, float* __restrict__ xT) {
    const int t = blockIdx.x * TPB + threadIdx.x;   // t in [0, K*M)
    const int k = t >> 5;
    const int m = t & 31;
    const float v = image[(size_t)m * Kdim + k];
    xT[t] = fmaxf(v, 0.0f) * (1.0f / 128.0f);
}

// ---------------------------------------------------------------------------
// Phase 1: split-K GEMM. Each block: 512 columns x all 32 rows x KC k's.
// x comes in via uniform scalar loads (xT pointer, indices independent of
// threadIdx) -> s_load; inner loop is ~pure v_fmac_f32 with SGPR src.
// ---------------------------------------------------------------------------
__global__ __launch_bounds__(TPB, 4)
void ht_gemm(const float* __restrict__ xT,     // (K, 32) relu'd, scaled
             const float* __restrict__ vote,   // (K, N) row-major
             float* __restrict__ parts,        // (KT, 32, N) partials
             int KC)                           // k's per chunk (multiple of U)
{
    const int tid    = threadIdx.x;
    const int ntile  = blockIdx.x % NTILES;
    const int kchunk = blockIdx.x / NTILES;
    const int k0     = kchunk * KC;
    const int n0     = ntile * NT + tid * NPT;

    const float* __restrict__ xk = xT + (size_t)k0 * Mdim;      // uniform
    const float* __restrict__ vp = vote + (size_t)k0 * Ndim + n0;

    float2 acc[Mdim];
    #pragma unroll
    for (int m = 0; m < Mdim; ++m) acc[m] = make_float2(0.f, 0.f);

    // Prefetch ring: U outstanding float2 V-loads per thread.
    float2 vbuf[U];
    #pragma unroll
    for (int u = 0; u < U; ++u)
        vbuf[u] = *reinterpret_cast<const float2*>(vp + (size_t)u * Ndim);

    for (int kk = 0; kk < KC - U; kk += U) {
        #pragma unroll
        for (int u = 0; u < U; ++u) {
            const float2 v = vbuf[u];
            vbuf[u] = *reinterpret_cast<const float2*>(vp + (size_t)(kk + U + u) * Ndim);
            const float* __restrict__ xrow = xk + (kk + u) * Mdim;  // uniform -> s_load
            #pragma unroll
            for (int m = 0; m < Mdim; ++m) {
                const float s = xrow[m];
                acc[m].x = fmaf(s, v.x, acc[m].x);
                acc[m].y = fmaf(s, v.y, acc[m].y);
            }
        }
    }
    // Epilogue: consume the last U buffered k's (no prefetch).
    {
        const int kk = KC - U;
        #pragma unroll
        for (int u = 0; u < U; ++u) {
            const float2 v = vbuf[u];
            const float* __restrict__ xrow = xk + (kk + u) * Mdim;
            #pragma unroll
            for (int m = 0; m < Mdim; ++m) {
                const float s = xrow[m];
                acc[m].x = fmaf(s, v.x, acc[m].x);
                acc[m].y = fmaf(s, v.y, acc[m].y);
            }
        }
    }

    float* p = parts + ((size_t)kchunk * Mdim) * Ndim + n0;
    #pragma unroll
    for (int m = 0; m < Mdim; ++m)
        *reinterpret_cast<float2*>(p + (size_t)m * Ndim) = acc[m];
}

// ---------------------------------------------------------------------------
// Phase 2: out[i] = sum_c parts[c][i]  (float4 per thread, coalesced)
// ---------------------------------------------------------------------------
__global__ __launch_bounds__(TPB)
void ht_reduce(const float* __restrict__ parts, float* __restrict__ out, int KT) {
    const size_t i4 = (size_t)blockIdx.x * TPB + threadIdx.x;   // float4 index
    const float4* p = reinterpret_cast<const float4*>(parts) + i4;
    float4 s = make_float4(0.f, 0.f, 0.f, 0.f);
    constexpr size_t stride4 = (size_t)Mdim * Ndim / 4;
    for (int c = 0; c < KT; ++c) {
        const float4 v = p[(size_t)c * stride4];
        s.x += v.x; s.y += v.y; s.z += v.z; s.w += v.w;
    }
    reinterpret_cast<float4*>(out)[i4] = s;
}

// ---------------------------------------------------------------------------
// Fallback (tiny ws): original atomic version — correct, slower.
// ---------------------------------------------------------------------------
__global__ __launch_bounds__(TPB)
void ht_gemm_atomic(const float* __restrict__ image, const float* __restrict__ vote,
                    float* __restrict__ out) {
    __shared__ float xs[256 * Mdim];
    const int tid = threadIdx.x;
    const int ntile = blockIdx.x % 16;
    const int k0 = (blockIdx.x / 16) * 256;
    const int n0 = ntile * 1024 + tid * 4;
    for (int idx = tid; idx < 256 * Mdim; idx += TPB) {
        const int kk = idx >> 5, m = idx & 31;
        xs[idx] = fmaxf(image[(size_t)m * Kdim + (k0 + kk)], 0.0f) * (1.0f / 128.0f);
    }
    __syncthreads();
    float4 acc[Mdim];
    #pragma unroll
    for (int m = 0; m < Mdim; ++m) acc[m] = make_float4(0.f, 0.f, 0.f, 0.f);
    const float* vptr = vote + (size_t)k0 * Ndim + n0;
    for (int kk = 0; kk < 256; ++kk) {
        const float4 v = *reinterpret_cast<const float4*>(vptr);
        vptr += Ndim;
        #pragma unroll
        for (int m = 0; m < Mdim; ++m) {
            const float s = xs[kk * Mdim + m];
            acc[m].x = fmaf(s, v.x, acc[m].x); acc[m].y = fmaf(s, v.y, acc[m].y);
            acc[m].z = fmaf(s, v.z, acc[m].z); acc[m].w = fmaf(s, v.w, acc[m].w);
        }
    }
    #pragma unroll
    for (int m = 0; m < Mdim; ++m) {
        float* o = out + (size_t)m * Ndim + n0;
        unsafeAtomicAdd(o + 0, acc[m].x); unsafeAtomicAdd(o + 1, acc[m].y);
        unsafeAtomicAdd(o + 2, acc[m].z); unsafeAtomicAdd(o + 3, acc[m].w);
    }
}

extern "C" void kernel_launch(void* const* d_in, const int* in_sizes, int n_in,
                              void* d_out, int out_size, void* d_ws, size_t ws_size,
                              hipStream_t stream) {
    const float* image = (const float*)d_in[0];   // (32, 16384)
    const float* vote  = (const float*)d_in[1];   // (16384, 16384)
    float* out = (float*)d_out;                   // (32, 16384)

    const size_t xt_bytes    = (size_t)Kdim * Mdim * sizeof(float);        // 2 MB
    const size_t chunk_bytes = (size_t)Mdim * Ndim * sizeof(float);        // 2 MB

    int KT = 0;
    for (int cand : {32, 16, 8, 4, 2}) {
        if (xt_bytes + (size_t)cand * chunk_bytes <= ws_size) { KT = cand; break; }
    }

    if (KT == 0) {
        // ws too small for split-K partials: atomic fallback.
        (void)hipMemsetAsync(out, 0, (size_t)out_size * sizeof(float), stream);
        ht_gemm_atomic<<<dim3(16 * 64), TPB, 0, stream>>>(image, vote, out);
        return;
    }

    float* xT    = (float*)d_ws;
    float* parts = (float*)((char*)d_ws + xt_bytes);
    const int KC = Kdim / KT;   // 512..8192, multiple of U

    build_xt<<<dim3((Kdim * Mdim) / TPB), TPB, 0, stream>>>(image, xT);
    ht_gemm<<<dim3(NTILES * KT), TPB, 0, stream>>>(xT, vote, parts, KC);
    ht_reduce<<<dim3((Mdim * Ndim) / (4 * TPB)), TPB, 0, stream>>>(parts, out, KT);
}